// Round 1
// baseline (102.065 us; speedup 1.0000x reference)
//
#include <hip/hip_runtime.h>

// Tensor-train forward, B=4096 N=8 F=64 D=64 C=10.
// Strategy: right-to-left bond-vector chain v (per-sample, D=64), each step a
// f16 MFMA GEMM  W[(p,l),s] = A_i'[(p,l),r] * v[s,r]  (M=4096,N=16,K=64) with
// the x[s,p]-weighted p-reduction fused into the D-fragment epilogue.
// Cores are pre-converted to f16 and pre-swizzled into MFMA A-fragment order
// by a prologue kernel so A-fragments load as coalesced dwordx4 from L2.

typedef _Float16 half8 __attribute__((ext_vector_type(8)));
typedef _Float16 half4 __attribute__((ext_vector_type(4)));
typedef float f32x4 __attribute__((ext_vector_type(4)));

#define LAST_OFF   0          // 4 tiles * 2 kt * 64 lanes * 8 halves = 4096
#define MID_OFF    4096
#define MID_SZ     262144     // per mid core: 256 tiles * 2 * 64 * 8
#define FIRST_OFF  1576960    // 4096 + 6*262144
#define N_FRAGS    3208       // 8 (last) + 3072 (mid) + 128 (first)

// ---------- prologue: fp32 cores -> f16, MFMA-A-fragment swizzled ----------
// A-frag (16x16x32 f16): lane holds A[m=lane&15][k=(lane>>4)*8 + j], j=0..7.
__global__ __launch_bounds__(256) void tt_swz(
    const float* __restrict__ cf,   // core_first (10,64,64)  [c][p][r]
    const float* __restrict__ cm,   // cores_mid  (6,64,64,64)[ci][l][p][r]
    const float* __restrict__ cl,   // core_last  (64,64)     [l][p]
    _Float16* __restrict__ ws)
{
  int gid = blockIdx.x * 256 + threadIdx.x;
  if (gid >= N_FRAGS * 64) return;
  int lane = gid & 63, frag = gid >> 6;
  int quad = lane >> 4, m16 = lane & 15;
  half8 hv;
  _Float16* dst;
  if (frag < 8) {                       // core_last: rows l (4 tiles), k = p
    int t = frag >> 1, kt = frag & 1;
    int l = t * 16 + m16;
    const float* s = cl + l * 64 + kt * 32 + quad * 8;
#pragma unroll
    for (int j = 0; j < 8; ++j) hv[j] = (_Float16)s[j];
    dst = ws + LAST_OFF + (size_t)((t * 2 + kt) * 64 + lane) * 8;
  } else if (frag < 8 + 3072) {         // mid cores: rows (p,l), k = r
    int f2 = frag - 8;
    int ci = f2 >> 9, rem = f2 & 511;
    int t = rem >> 1, kt = rem & 1;
    int l = (t & 3) * 16 + m16, p = t >> 2;
    const float* s = cm + (((size_t)ci * 64 + l) * 64 + p) * 64 + kt * 32 + quad * 8;
#pragma unroll
    for (int j = 0; j < 8; ++j) hv[j] = (_Float16)s[j];
    dst = ws + MID_OFF + (size_t)ci * MID_SZ + (size_t)(rem * 64 + lane) * 8;
  } else {                              // core_first: rows (p, c padded to 16), k = r
    int f2 = frag - 3080;
    int t = f2 >> 1, kt = f2 & 1;
    int c = m16, p = t;
    if (c < 10) {
      const float* s = cf + ((size_t)(c * 64 + p)) * 64 + kt * 32 + quad * 8;
#pragma unroll
      for (int j = 0; j < 8; ++j) hv[j] = (_Float16)s[j];
    } else {
#pragma unroll
      for (int j = 0; j < 8; ++j) hv[j] = (_Float16)0.f;
    }
    dst = ws + FIRST_OFF + (size_t)((t * 2 + kt) * 64 + lane) * 8;
  }
  *(half8*)dst = hv;
}

// ---------------------------- main chain kernel ----------------------------
// 256 blocks x 512 threads (8 waves). Block owns 16 samples end-to-end.
__global__ __launch_bounds__(512) void tt_main(
    const float* __restrict__ x,        // (4096, 8, 64)
    const _Float16* __restrict__ ws,
    float* __restrict__ out)            // (4096, 10)
{
  __shared__ __align__(16) float Xs[512 * 17];          // [n*64+p][s], padded
  __shared__ __align__(16) _Float16 Vt[2][16][72];      // [half][s][l], padded
  __shared__ __align__(16) float Red[8][16][16];        // [wave][c][s]
  const int tid = threadIdx.x;
  const int w = tid >> 6, lane = tid & 63;
  const int quad = lane >> 4, sl = lane & 15;
  const int blk = blockIdx.x;

  // ---- stage x for the block's 16 samples, transposed to [n*64+p][s] ----
  {
    const float* xb = x + (size_t)blk * 16 * 512;
    int s = tid & 15, b0 = (tid >> 4) * 4;
#pragma unroll
    for (int k = 0; k < 4; ++k) {
      int base = b0 + k * 128;                       // n*64+p
      float4 v = *(const float4*)(xb + s * 512 + base);
      Xs[(base + 0) * 17 + s] = v.x;
      Xs[(base + 1) * 17 + s] = v.y;
      Xs[(base + 2) * 17 + s] = v.z;
      Xs[(base + 3) * 17 + s] = v.w;
    }
  }
  __syncthreads();

  // ---- GEMM1: v7[l,s] = sum_p core_last[l,p] x[s,7,p]; K split over waves
  {
    int kt = w >> 2, tt = w & 3;
    half8 b;
#pragma unroll
    for (int j = 0; j < 8; ++j)
      b[j] = (_Float16)Xs[(448 + kt * 32 + quad * 8 + j) * 17 + sl];
    half8 a = *(const half8*)(ws + LAST_OFF + (size_t)((tt * 2 + kt) * 64 + lane) * 8);
    f32x4 d = {0.f, 0.f, 0.f, 0.f};
    d = __builtin_amdgcn_mfma_f32_16x16x32_f16(a, b, d, 0, 0, 0);
    half4 hv;
#pragma unroll
    for (int r = 0; r < 4; ++r) hv[r] = (_Float16)d[r];
    *(half4*)&Vt[kt][sl][tt * 16 + quad * 4] = hv;    // partial half kt
  }
  __syncthreads();

  const int h = w >> 2, g = w & 3;
  // ---- 6 middle steps (right-to-left: cores_mid[5] .. cores_mid[0]) ----
  for (int step = 0; step < 6; ++step) {
    int ci = 5 - step;
    const _Float16* base = ws + MID_OFF + (size_t)ci * MID_SZ;
    // B-frags: v[r][s], summing the two partial halves
    half8 b0 = *(const half8*)&Vt[0][sl][quad * 8];
    half8 b0p = *(const half8*)&Vt[1][sl][quad * 8];
    half8 b1 = *(const half8*)&Vt[0][sl][32 + quad * 8];
    half8 b1p = *(const half8*)&Vt[1][sl][32 + quad * 8];
    b0 = b0 + b0p; b1 = b1 + b1p;
    __syncthreads();                                  // reads done before overwrite
    float a0c = 0.f, a1c = 0.f, a2c = 0.f, a3c = 0.f;
    const int xrow = (ci + 1) * 64;
#pragma unroll 8
    for (int j = 0; j < 32; ++j) {
      int t = 8 * j + w;                              // tile: p = t>>2, lchunk = (t&3)*16
      int p = t >> 2;
      const _Float16* fp = base + (size_t)t * 1024 + (size_t)lane * 8;
      half8 A0 = *(const half8*)fp;
      half8 A1 = *(const half8*)(fp + 512);
      f32x4 dd = {0.f, 0.f, 0.f, 0.f};
      dd = __builtin_amdgcn_mfma_f32_16x16x32_f16(A0, b0, dd, 0, 0, 0);
      dd = __builtin_amdgcn_mfma_f32_16x16x32_f16(A1, b1, dd, 0, 0, 0);
      float xv = Xs[(xrow + p) * 17 + sl];            // x[s, ci+1, p]
      a0c += xv * dd[0]; a1c += xv * dd[1];
      a2c += xv * dd[2]; a3c += xv * dd[3];
    }
    half4 hv;
    hv[0] = (_Float16)a0c; hv[1] = (_Float16)a1c;
    hv[2] = (_Float16)a2c; hv[3] = (_Float16)a3c;
    *(half4*)&Vt[h][sl][g * 16 + quad * 4] = hv;      // partial half h (p-split)
    __syncthreads();
  }

  // ---- final: out[c,s] = sum_{p,r} core_first[c,p,r] x[s,0,p] v[r] ----
  {
    half8 b0 = *(const half8*)&Vt[0][sl][quad * 8];
    half8 b0p = *(const half8*)&Vt[1][sl][quad * 8];
    half8 b1 = *(const half8*)&Vt[0][sl][32 + quad * 8];
    half8 b1p = *(const half8*)&Vt[1][sl][32 + quad * 8];
    b0 = b0 + b0p; b1 = b1 + b1p;
    float f0 = 0.f, f1 = 0.f, f2 = 0.f, f3 = 0.f;
#pragma unroll
    for (int j = 0; j < 8; ++j) {
      int t = 8 * j + w;                              // tile t = p
      const _Float16* fp = ws + FIRST_OFF + (size_t)t * 1024 + (size_t)lane * 8;
      half8 A0 = *(const half8*)fp;
      half8 A1 = *(const half8*)(fp + 512);
      f32x4 dd = {0.f, 0.f, 0.f, 0.f};
      dd = __builtin_amdgcn_mfma_f32_16x16x32_f16(A0, b0, dd, 0, 0, 0);
      dd = __builtin_amdgcn_mfma_f32_16x16x32_f16(A1, b1, dd, 0, 0, 0);
      float xv = Xs[t * 17 + sl];                     // x[s, 0, p]
      f0 += xv * dd[0]; f1 += xv * dd[1];
      f2 += xv * dd[2]; f3 += xv * dd[3];
    }
    Red[w][quad * 4 + 0][sl] = f0;
    Red[w][quad * 4 + 1][sl] = f1;
    Red[w][quad * 4 + 2][sl] = f2;
    Red[w][quad * 4 + 3][sl] = f3;
  }
  __syncthreads();
  if (tid < 256) {
    int c = tid >> 4, s = tid & 15;
    float sum = 0.f;
#pragma unroll
    for (int ww = 0; ww < 8; ++ww) sum += Red[ww][c][s];
    if (c < 10) out[((size_t)blk * 16 + s) * 10 + c] = sum;
  }
}

extern "C" void kernel_launch(void* const* d_in, const int* in_sizes, int n_in,
                              void* d_out, int out_size, void* d_ws, size_t ws_size,
                              hipStream_t stream) {
  const float* x  = (const float*)d_in[0];   // (4096,8,64)
  const float* cf = (const float*)d_in[1];   // (10,64,64)
  const float* cm = (const float*)d_in[2];   // (6,64,64,64)
  const float* cl = (const float*)d_in[3];   // (64,64)
  _Float16* ws = (_Float16*)d_ws;            // needs ~3.3 MB
  float* out = (float*)d_out;
  tt_swz<<<dim3((N_FRAGS * 64 + 255) / 256), dim3(256), 0, stream>>>(cf, cm, cl, ws);
  tt_main<<<dim3(256), dim3(512), 0, stream>>>(x, ws, out);
}

// Round 2
// 101.571 us; speedup vs baseline: 1.0049x; 1.0049x over previous
//
#include <hip/hip_runtime.h>

// Tensor-train forward, B=4096 N=8 F=64 D=64 C=10.
// v-chain right-to-left; per step a f16 MFMA GEMM W[(p,l),s]=A'[(p,l),r]*v[s,r]
// with the x[s,p]-weighted p-reduction fused in the D-fragment epilogue.
// R1: 32 samples/block (128 blocks x 1024 thr) -> each A-frag feeds 4 MFMAs,
// halving L2 A-traffic vs 16-sample blocks. x staged as f16; partial-v combine
// stage makes B-frags single ds_read_b128.

typedef _Float16 half8 __attribute__((ext_vector_type(8)));
typedef _Float16 half4 __attribute__((ext_vector_type(4)));
typedef _Float16 half2v __attribute__((ext_vector_type(2)));
typedef float f32x4 __attribute__((ext_vector_type(4)));

#define LAST_OFF   0          // 4 tiles * 2 kt * 64 lanes * 8 halves
#define MID_OFF    4096
#define MID_SZ     262144     // per mid core: 256 tiles * 2 * 64 * 8
#define FIRST_OFF  1576960    // 4096 + 6*262144
#define N_FRAGS    3208

// ---------- prologue: fp32 cores -> f16, MFMA-A-fragment swizzled ----------
__global__ __launch_bounds__(256) void tt_swz(
    const float* __restrict__ cf,   // core_first (10,64,64)  [c][p][r]
    const float* __restrict__ cm,   // cores_mid  (6,64,64,64)[ci][l][p][r]
    const float* __restrict__ cl,   // core_last  (64,64)     [l][p]
    _Float16* __restrict__ ws)
{
  int gid = blockIdx.x * 256 + threadIdx.x;
  if (gid >= N_FRAGS * 64) return;
  int lane = gid & 63, frag = gid >> 6;
  int quad = lane >> 4, m16 = lane & 15;
  half8 hv;
  _Float16* dst;
  if (frag < 8) {                       // core_last: rows l (4 tiles), k = p
    int t = frag >> 1, kt = frag & 1;
    int l = t * 16 + m16;
    const float* s = cl + l * 64 + kt * 32 + quad * 8;
#pragma unroll
    for (int j = 0; j < 8; ++j) hv[j] = (_Float16)s[j];
    dst = ws + LAST_OFF + (size_t)((t * 2 + kt) * 64 + lane) * 8;
  } else if (frag < 8 + 3072) {         // mid cores: rows (p,l), k = r
    int f2 = frag - 8;
    int ci = f2 >> 9, rem = f2 & 511;
    int t = rem >> 1, kt = rem & 1;
    int l = (t & 3) * 16 + m16, p = t >> 2;
    const float* s = cm + (((size_t)ci * 64 + l) * 64 + p) * 64 + kt * 32 + quad * 8;
#pragma unroll
    for (int j = 0; j < 8; ++j) hv[j] = (_Float16)s[j];
    dst = ws + MID_OFF + (size_t)ci * MID_SZ + (size_t)(rem * 64 + lane) * 8;
  } else {                              // core_first: rows c (pad 16), k = r
    int f2 = frag - 3080;
    int t = f2 >> 1, kt = f2 & 1;
    int c = m16, p = t;
    if (c < 10) {
      const float* s = cf + ((size_t)(c * 64 + p)) * 64 + kt * 32 + quad * 8;
#pragma unroll
      for (int j = 0; j < 8; ++j) hv[j] = (_Float16)s[j];
    } else {
#pragma unroll
      for (int j = 0; j < 8; ++j) hv[j] = (_Float16)0.f;
    }
    dst = ws + FIRST_OFF + (size_t)((t * 2 + kt) * 64 + lane) * 8;
  }
  *(half8*)dst = hv;
}

// ------------------- main chain: 128 blocks x 1024 threads -----------------
__global__ __launch_bounds__(1024) void tt_main(
    const float* __restrict__ x,        // (4096, 8, 64)
    const _Float16* __restrict__ ws,
    float* __restrict__ out)            // (4096, 10)
{
  __shared__ __align__(16) _Float16 Xs[512][33];     // [n*64+p][s] f16
  __shared__ __align__(16) _Float16 Vt[4][32][72];   // partials [part][s][l]
  __shared__ __align__(16) _Float16 Vc[32][72];      // combined  [s][r]
  const int tid = threadIdx.x;
  const int w = tid >> 6, lane = tid & 63;
  const int quad = lane >> 4, sl = lane & 15;
  const int blk = blockIdx.x;

  // ---- stage x (32 samples x 512 floats -> f16), zero spare Vt partials ----
  {
    const float* xb = x + (size_t)blk * 32 * 512;
    int s = tid >> 5, q = tid & 31;
#pragma unroll
    for (int k = 0; k < 4; ++k) {
      int f4 = q + 32 * k;
      float4 v = *(const float4*)(xb + (size_t)s * 512 + (size_t)f4 * 4);
      int row = f4 * 4;
      Xs[row + 0][s] = (_Float16)v.x;
      Xs[row + 1][s] = (_Float16)v.y;
      Xs[row + 2][s] = (_Float16)v.z;
      Xs[row + 3][s] = (_Float16)v.w;
    }
    _Float16* vz = &Vt[2][0][0];
    for (int idx = tid; idx < 2 * 32 * 72; idx += 1024) vz[idx] = (_Float16)0.f;
  }
  __syncthreads();

  // ---- GEMM1 (core_last): 16 wave-tasks = (st, kt, tt) ----
  {
    int st = w >> 3, kt = (w >> 2) & 1, tt = w & 3;
    half8 b;
#pragma unroll
    for (int j = 0; j < 8; ++j)
      b[j] = Xs[448 + kt * 32 + quad * 8 + j][st * 16 + sl];
    half8 a = *(const half8*)(ws + LAST_OFF + (size_t)((tt * 2 + kt) * 64 + lane) * 8);
    f32x4 d = {0.f, 0.f, 0.f, 0.f};
    d = __builtin_amdgcn_mfma_f32_16x16x32_f16(a, b, d, 0, 0, 0);
    half4 hv;
#pragma unroll
    for (int r = 0; r < 4; ++r) hv[r] = (_Float16)d[r];
    *(half4*)&Vt[kt][st * 16 + sl][tt * 16 + quad * 4] = hv;
  }
  __syncthreads();
  // combine partials -> Vc
  {
    int s = tid >> 5, rp = tid & 31;
    float r0 = 0.f, r1 = 0.f;
#pragma unroll
    for (int p = 0; p < 4; ++p) {
      half2v h = *(const half2v*)&Vt[p][s][rp * 2];
      r0 += (float)h[0]; r1 += (float)h[1];
    }
    half2v o; o[0] = (_Float16)r0; o[1] = (_Float16)r1;
    *(half2v*)&Vc[s][rp * 2] = o;
  }
  __syncthreads();

  const int g = w & 3, part = w >> 2;
  // ---- 6 middle steps (cores_mid[5] .. cores_mid[0]) ----
  for (int step = 0; step < 6; ++step) {
    int ci = 5 - step;
    // B-frags for both sample tiles & k-halves (single ds_read_b128 each)
    half8 b00 = *(const half8*)&Vc[sl][quad * 8];
    half8 b01 = *(const half8*)&Vc[sl][32 + quad * 8];
    half8 b10 = *(const half8*)&Vc[16 + sl][quad * 8];
    half8 b11 = *(const half8*)&Vc[16 + sl][32 + quad * 8];
    const _Float16* wl = ws + MID_OFF + (size_t)ci * MID_SZ
                       + (size_t)w * 1024 + (size_t)lane * 8;
    float c00 = 0.f, c01 = 0.f, c02 = 0.f, c03 = 0.f;
    float c10 = 0.f, c11 = 0.f, c12 = 0.f, c13 = 0.f;
    const int xrow = (ci + 1) * 64;
#pragma unroll 4
    for (int j = 0; j < 16; ++j) {
      int t = j * 16 + w;                       // p = t>>2 == 4j + (w>>2)
      int p = t >> 2;
      const _Float16* fp = wl + (size_t)j * 16384;
      half8 A0 = *(const half8*)fp;
      half8 A1 = *(const half8*)(fp + 512);
      f32x4 d0 = {0.f, 0.f, 0.f, 0.f}, d1 = {0.f, 0.f, 0.f, 0.f};
      d0 = __builtin_amdgcn_mfma_f32_16x16x32_f16(A0, b00, d0, 0, 0, 0);
      d0 = __builtin_amdgcn_mfma_f32_16x16x32_f16(A1, b01, d0, 0, 0, 0);
      d1 = __builtin_amdgcn_mfma_f32_16x16x32_f16(A0, b10, d1, 0, 0, 0);
      d1 = __builtin_amdgcn_mfma_f32_16x16x32_f16(A1, b11, d1, 0, 0, 0);
      float xv0 = (float)Xs[xrow + p][sl];
      float xv1 = (float)Xs[xrow + p][16 + sl];
      c00 += xv0 * d0[0]; c01 += xv0 * d0[1]; c02 += xv0 * d0[2]; c03 += xv0 * d0[3];
      c10 += xv1 * d1[0]; c11 += xv1 * d1[1]; c12 += xv1 * d1[2]; c13 += xv1 * d1[3];
    }
    half4 h0, h1;
    h0[0] = (_Float16)c00; h0[1] = (_Float16)c01; h0[2] = (_Float16)c02; h0[3] = (_Float16)c03;
    h1[0] = (_Float16)c10; h1[1] = (_Float16)c11; h1[2] = (_Float16)c12; h1[3] = (_Float16)c13;
    *(half4*)&Vt[part][sl][g * 16 + quad * 4] = h0;
    *(half4*)&Vt[part][16 + sl][g * 16 + quad * 4] = h1;
    __syncthreads();
    {
      int s = tid >> 5, rp = tid & 31;
      float r0 = 0.f, r1 = 0.f;
#pragma unroll
      for (int p = 0; p < 4; ++p) {
        half2v h = *(const half2v*)&Vt[p][s][rp * 2];
        r0 += (float)h[0]; r1 += (float)h[1];
      }
      half2v o; o[0] = (_Float16)r0; o[1] = (_Float16)r1;
      *(half2v*)&Vc[s][rp * 2] = o;
    }
    __syncthreads();
  }

  // ---- final (core_first): 8 waves, 64 tiles (t = p); Red overlays Vt ----
  float* Red = (float*)&Vt[0][0][0];              // [8][10][32]
  if (w < 8) {
    half8 b00 = *(const half8*)&Vc[sl][quad * 8];
    half8 b01 = *(const half8*)&Vc[sl][32 + quad * 8];
    half8 b10 = *(const half8*)&Vc[16 + sl][quad * 8];
    half8 b11 = *(const half8*)&Vc[16 + sl][32 + quad * 8];
    float f00 = 0.f, f01 = 0.f, f02 = 0.f, f03 = 0.f;
    float f10 = 0.f, f11 = 0.f, f12 = 0.f, f13 = 0.f;
#pragma unroll
    for (int j = 0; j < 8; ++j) {
      int t = j * 8 + w;
      const _Float16* fp = ws + FIRST_OFF + (size_t)t * 1024 + (size_t)lane * 8;
      half8 A0 = *(const half8*)fp;
      half8 A1 = *(const half8*)(fp + 512);
      f32x4 d0 = {0.f, 0.f, 0.f, 0.f}, d1 = {0.f, 0.f, 0.f, 0.f};
      d0 = __builtin_amdgcn_mfma_f32_16x16x32_f16(A0, b00, d0, 0, 0, 0);
      d0 = __builtin_amdgcn_mfma_f32_16x16x32_f16(A1, b01, d0, 0, 0, 0);
      d1 = __builtin_amdgcn_mfma_f32_16x16x32_f16(A0, b10, d1, 0, 0, 0);
      d1 = __builtin_amdgcn_mfma_f32_16x16x32_f16(A1, b11, d1, 0, 0, 0);
      float xv0 = (float)Xs[t][sl];
      float xv1 = (float)Xs[t][16 + sl];
      f00 += xv0 * d0[0]; f01 += xv0 * d0[1]; f02 += xv0 * d0[2]; f03 += xv0 * d0[3];
      f10 += xv1 * d1[0]; f11 += xv1 * d1[1]; f12 += xv1 * d1[2]; f13 += xv1 * d1[3];
    }
    float a0[4] = {f00, f01, f02, f03};
    float a1[4] = {f10, f11, f12, f13};
#pragma unroll
    for (int r = 0; r < 4; ++r) {
      int c = quad * 4 + r;
      if (c < 10) {
        Red[(w * 10 + c) * 32 + sl] = a0[r];
        Red[(w * 10 + c) * 32 + 16 + sl] = a1[r];
      }
    }
  }
  __syncthreads();
  if (tid < 320) {
    int c = tid >> 5, s = tid & 31;
    float sum = 0.f;
#pragma unroll
    for (int ww = 0; ww < 8; ++ww) sum += Red[(ww * 10 + c) * 32 + s];
    out[((size_t)blk * 32 + s) * 10 + c] = sum;
  }
}

extern "C" void kernel_launch(void* const* d_in, const int* in_sizes, int n_in,
                              void* d_out, int out_size, void* d_ws, size_t ws_size,
                              hipStream_t stream) {
  const float* x  = (const float*)d_in[0];   // (4096,8,64)
  const float* cf = (const float*)d_in[1];   // (10,64,64)
  const float* cm = (const float*)d_in[2];   // (6,64,64,64)
  const float* cl = (const float*)d_in[3];   // (64,64)
  _Float16* ws = (_Float16*)d_ws;            // ~3.3 MB used
  float* out = (float*)d_out;
  tt_swz<<<dim3((N_FRAGS * 64 + 255) / 256), dim3(256), 0, stream>>>(cf, cm, cl, ws);
  tt_main<<<dim3(128), dim3(1024), 0, stream>>>(x, ws, out);
}